// Round 1
// baseline (1533.074 us; speedup 1.0000x reference)
//
#include <hip/hip_runtime.h>
#include <hip/hip_bf16.h>

#define NN 100000
#define NE 1600000

typedef __attribute__((ext_vector_type(8))) short short8;
typedef __attribute__((ext_vector_type(4))) float f32x4;

static __device__ __forceinline__ unsigned short f2bf(float f) {
    unsigned u = __float_as_uint(f);
    unsigned r = (u + 0x7fffu + ((u >> 16) & 1u)) >> 16;
    return (unsigned short)r;
}
static __device__ __forceinline__ float bf2f(unsigned short s) {
    return __uint_as_float(((unsigned)s) << 16);
}

__global__ void k_deg_init(float* deg) {
    int i = blockIdx.x * blockDim.x + threadIdx.x;
    if (i < NN) deg[i] = 1.0f;  // self-loop
}
__global__ void k_deg_count(const int* __restrict__ ei, float* deg) {
    int e = blockIdx.x * blockDim.x + threadIdx.x;
    if (e < NE) atomicAdd(&deg[ei[NE + e]], 1.0f);
}
__global__ void k_dinv(float* deg) {
    int i = blockIdx.x * blockDim.x + threadIdx.x;
    if (i < NN) deg[i] = rsqrtf(deg[i]);
}

// h = (prelu?)(in) @ W  [N x K] @ [K x 64]
// writes: hout (bf16, raw matmul result) and agg = h*dinv^2 + bias (self-loop init)
template <int K, bool PRELU>
__global__ __launch_bounds__(256) void k_mm(const float* __restrict__ in,
                                            const float* __restrict__ W,
                                            const float* __restrict__ bias,
                                            const float* __restrict__ alpha,
                                            const float* __restrict__ dinv,
                                            unsigned short* __restrict__ hout,
                                            float* __restrict__ agg) {
    constexpr int KP = K + 8;  // pad: lane stride 2*KP B -> 2-way bank alias (free)
    __shared__ unsigned short Wt[64 * KP];
    __shared__ float alph[64];
    int tid = threadIdx.x;
    for (int idx = tid; idx < K * 64; idx += 256) {
        int k = idx >> 6, n = idx & 63;
        Wt[n * KP + k] = f2bf(W[idx]);
    }
    if (PRELU && tid < 64) alph[tid] = alpha[tid];
    __syncthreads();

    int wave = tid >> 6, lane = tid & 63;
    int m = lane & 15, q = lane >> 4;
    int n0 = blockIdx.x * 64 + wave * 16;

    f32x4 acc[4] = {{0.f,0.f,0.f,0.f},{0.f,0.f,0.f,0.f},{0.f,0.f,0.f,0.f},{0.f,0.f,0.f,0.f}};
    int row = n0 + m;
    int rowc = row < NN ? row : NN - 1;
    const float* xr = in + (long)rowc * K;

    #pragma unroll
    for (int kk = 0; kk < K / 32; ++kk) {
        const float4* p = (const float4*)(xr + kk * 32 + q * 8);
        float4 v0 = p[0], v1 = p[1];
        float xv[8] = {v0.x, v0.y, v0.z, v0.w, v1.x, v1.y, v1.z, v1.w};
        short8 afrag;
        #pragma unroll
        for (int i2 = 0; i2 < 8; ++i2) {
            float v = xv[i2];
            if (PRELU) {
                int kidx = kk * 32 + q * 8 + i2;
                v = v >= 0.f ? v : alph[kidx] * v;
            }
            afrag[i2] = (short)f2bf(v);
        }
        #pragma unroll
        for (int nt = 0; nt < 4; ++nt) {
            const short8* bp = (const short8*)&Wt[(nt * 16 + m) * KP + kk * 32 + q * 8];
            acc[nt] = __builtin_amdgcn_mfma_f32_16x16x32_bf16(afrag, *bp, acc[nt], 0, 0, 0);
        }
    }

    // epilogue: D layout col=lane&15, row=(lane>>4)*4+reg  [m89-verified]
    float bcol[4];
    #pragma unroll
    for (int nt = 0; nt < 4; ++nt) bcol[nt] = bias[nt * 16 + m];
    #pragma unroll
    for (int reg = 0; reg < 4; ++reg) {
        int r = q * 4 + reg;
        int node = n0 + r;
        if (node < NN) {
            float dv = dinv[node];
            float d2 = dv * dv;
            #pragma unroll
            for (int nt = 0; nt < 4; ++nt) {
                float val = acc[nt][reg];
                int col = nt * 16 + m;
                hout[(long)node * 64 + col] = f2bf(val);
                agg[(long)node * 64 + col] = val * d2 + bcol[nt];
            }
        }
    }
}

// one half-wave (32 lanes) per edge; lane covers 2 columns (one packed bf16 dword)
__global__ __launch_bounds__(256) void k_edges(const int* __restrict__ ei,
                                               const unsigned short* __restrict__ h,
                                               const float* __restrict__ dinv,
                                               float* __restrict__ agg) {
    int e = blockIdx.x * 8 + (threadIdx.x >> 5);
    int l = threadIdx.x & 31;
    if (e < NE) {
        int s = ei[e];
        int d = ei[NE + e];
        float norm = dinv[s] * dinv[d];
        unsigned hv = *(const unsigned*)(h + (long)s * 64 + l * 2);
        float f0 = bf2f((unsigned short)(hv & 0xffffu)) * norm;
        float f1 = bf2f((unsigned short)(hv >> 16)) * norm;
        atomicAdd(&agg[(long)d * 64 + l * 2], f0);
        atomicAdd(&agg[(long)d * 64 + l * 2 + 1], f1);
    }
}

__global__ void k_prelu(float* out, const float* __restrict__ alpha) {
    int i = blockIdx.x * blockDim.x + threadIdx.x;
    if (i < NN * 64) {
        float v = out[i];
        float a = alpha[i & 63];
        out[i] = v >= 0.f ? v : a * v;
    }
}

extern "C" void kernel_launch(void* const* d_in, const int* in_sizes, int n_in,
                              void* d_out, int out_size, void* d_ws, size_t ws_size,
                              hipStream_t stream) {
    const float* x     = (const float*)d_in[0];
    const int*   ei    = (const int*)d_in[1];
    const float* W1    = (const float*)d_in[2];
    const float* b1    = (const float*)d_in[3];
    const float* W2    = (const float*)d_in[4];
    const float* b2    = (const float*)d_in[5];
    const float* alpha = (const float*)d_in[6];
    float* out = (float*)d_out;

    char* ws = (char*)d_ws;
    float* dinv = (float*)ws;                                   // 400,000 B
    unsigned short* hbf = (unsigned short*)(ws + 400384);       // 12,800,000 B (bf16 h)
    float* agg = (float*)(ws + 400384 + 12800000);              // 25,600,000 B (layer-1 agg)

    k_deg_init<<<(NN + 255) / 256, 256, 0, stream>>>(dinv);
    k_deg_count<<<(NE + 255) / 256, 256, 0, stream>>>(ei, dinv);
    k_dinv<<<(NN + 255) / 256, 256, 0, stream>>>(dinv);

    // layer 1: h1 = x@W1 ; agg1 = h1*dinv^2 + b1 ; += edge messages
    k_mm<128, false><<<(NN + 63) / 64, 256, 0, stream>>>(x, W1, b1, nullptr, dinv, hbf, agg);
    k_edges<<<NE / 8, 256, 0, stream>>>(ei, hbf, dinv, agg);

    // layer 2: z1 = prelu(agg1) fused into A-load; agg2 accumulated directly in d_out
    k_mm<64, true><<<(NN + 63) / 64, 256, 0, stream>>>(agg, W2, b2, alpha, dinv, hbf, out);
    k_edges<<<NE / 8, 256, 0, stream>>>(ei, hbf, dinv, out);

    k_prelu<<<(NN * 64 + 255) / 256, 256, 0, stream>>>(out, alpha);
}

// Round 2
// 443.176 us; speedup vs baseline: 3.4593x; 3.4593x over previous
//
#include <hip/hip_runtime.h>
#include <hip/hip_bf16.h>

#define NN 100000
#define NE 1600000

typedef __attribute__((ext_vector_type(8))) short short8;
typedef __attribute__((ext_vector_type(4))) float f32x4;

static __device__ __forceinline__ unsigned short f2bf(float f) {
    unsigned u = __float_as_uint(f);
    unsigned r = (u + 0x7fffu + ((u >> 16) & 1u)) >> 16;
    return (unsigned short)r;
}
static __device__ __forceinline__ float bf2f(unsigned short s) {
    return __uint_as_float(((unsigned)s) << 16);
}

// ---------- degree / CSR build ----------
__global__ void k_hist(const int* __restrict__ ei, int* __restrict__ cnt) {
    int e = blockIdx.x * blockDim.x + threadIdx.x;
    if (e < NE) atomicAdd(&cnt[ei[NE + e]], 1);
}
__global__ void k_dinv(const int* __restrict__ cnt, float* __restrict__ dinv) {
    int i = blockIdx.x * blockDim.x + threadIdx.x;
    if (i < NN) dinv[i] = rsqrtf((float)(cnt[i] + 1));  // +1 self-loop
}

// hierarchical exclusive scan: cnt[NN] -> pos[NN] (+ pos[NN]=NE set later)
__global__ __launch_bounds__(1024) void k_scan1(const int* __restrict__ cnt,
                                                int* __restrict__ pos,
                                                int* __restrict__ bsum) {
    __shared__ int s[1024];
    int tid = threadIdx.x;
    int i = blockIdx.x * 1024 + tid;
    int v = (i < NN) ? cnt[i] : 0;
    s[tid] = v;
    __syncthreads();
    #pragma unroll
    for (int off = 1; off < 1024; off <<= 1) {
        int t = (tid >= off) ? s[tid - off] : 0;
        __syncthreads();
        s[tid] += t;
        __syncthreads();
    }
    if (i < NN) pos[i] = s[tid] - v;  // exclusive
    if (tid == 1023) bsum[blockIdx.x] = s[1023];
}
__global__ __launch_bounds__(128) void k_scan2(int* __restrict__ bsum, int nb) {
    __shared__ int s[128];
    int tid = threadIdx.x;
    int v = (tid < nb) ? bsum[tid] : 0;
    s[tid] = v;
    __syncthreads();
    #pragma unroll
    for (int off = 1; off < 128; off <<= 1) {
        int t = (tid >= off) ? s[tid - off] : 0;
        __syncthreads();
        s[tid] += t;
        __syncthreads();
    }
    if (tid < nb) bsum[tid] = s[tid] - v;  // exclusive
}
__global__ __launch_bounds__(1024) void k_scan3(int* __restrict__ pos,
                                                const int* __restrict__ bsum,
                                                int* __restrict__ cur) {
    int tid = threadIdx.x;
    int i = blockIdx.x * 1024 + tid;
    if (i < NN) {
        int p = pos[i] + bsum[blockIdx.x];
        pos[i] = p;
        cur[i] = p;
    }
    if (i == 0) pos[NN] = NE;
}
__global__ void k_scatter(const int* __restrict__ ei, int* __restrict__ cur,
                          int* __restrict__ esrc) {
    int e = blockIdx.x * blockDim.x + threadIdx.x;
    if (e < NE) {
        int s = ei[e];
        int d = ei[NE + e];
        int p = atomicAdd(&cur[d], 1);
        esrc[p] = s;
    }
}

// ---------- h = in @ W  [N x K] @ [K x 64] -> bf16 ----------
template <int K>
__global__ __launch_bounds__(256) void k_mm(const float* __restrict__ in,
                                            const float* __restrict__ W,
                                            unsigned short* __restrict__ hout) {
    constexpr int KP = K + 8;  // 2-way bank alias only (free)
    __shared__ unsigned short Wt[64 * KP];
    int tid = threadIdx.x;
    for (int idx = tid; idx < K * 64; idx += 256) {
        int k = idx >> 6, n = idx & 63;
        Wt[n * KP + k] = f2bf(W[idx]);
    }
    __syncthreads();

    int wave = tid >> 6, lane = tid & 63;
    int m = lane & 15, q = lane >> 4;
    int n0 = blockIdx.x * 64 + wave * 16;

    f32x4 acc[4] = {{0.f,0.f,0.f,0.f},{0.f,0.f,0.f,0.f},{0.f,0.f,0.f,0.f},{0.f,0.f,0.f,0.f}};
    int row = n0 + m;
    int rowc = row < NN ? row : NN - 1;
    const float* xr = in + (long)rowc * K;

    #pragma unroll
    for (int kk = 0; kk < K / 32; ++kk) {
        const float4* p = (const float4*)(xr + kk * 32 + q * 8);
        float4 v0 = p[0], v1 = p[1];
        float xv[8] = {v0.x, v0.y, v0.z, v0.w, v1.x, v1.y, v1.z, v1.w};
        short8 afrag;
        #pragma unroll
        for (int i2 = 0; i2 < 8; ++i2) afrag[i2] = (short)f2bf(xv[i2]);
        #pragma unroll
        for (int nt = 0; nt < 4; ++nt) {
            const short8* bp = (const short8*)&Wt[(nt * 16 + m) * KP + kk * 32 + q * 8];
            acc[nt] = __builtin_amdgcn_mfma_f32_16x16x32_bf16(afrag, *bp, acc[nt], 0, 0, 0);
        }
    }

    // D layout: col=lane&15, row=(lane>>4)*4+reg  [m89-verified]
    #pragma unroll
    for (int reg = 0; reg < 4; ++reg) {
        int node = n0 + q * 4 + reg;
        if (node < NN) {
            #pragma unroll
            for (int nt = 0; nt < 4; ++nt)
                hout[(long)node * 64 + nt * 16 + m] = f2bf(acc[nt][reg]);
        }
    }
}

// ---------- per-node aggregation: half-wave per node, fp32 registers ----------
__global__ __launch_bounds__(256) void k_agg(const int* __restrict__ row_ptr,
                                             const int* __restrict__ esrc,
                                             const unsigned short* __restrict__ h,
                                             const float* __restrict__ dinv,
                                             const float* __restrict__ bias,
                                             const float* __restrict__ alpha,
                                             float* __restrict__ out) {
    int node = blockIdx.x * 8 + (threadIdx.x >> 5);
    int l = threadIdx.x & 31;
    if (node >= NN) return;
    int start = row_ptr[node], end = row_ptr[node + 1];
    float dn = dinv[node];

    // self-loop: norm = dinv[node]^2
    unsigned hv = *(const unsigned*)(h + (long)node * 64 + l * 2);
    float d2 = dn * dn;
    float a0 = bf2f((unsigned short)(hv & 0xffffu)) * d2;
    float a1 = bf2f((unsigned short)(hv >> 16)) * d2;

    int i = start;
    for (; i + 1 < end; i += 2) {
        int s0 = esrc[i], s1 = esrc[i + 1];
        float n0 = dinv[s0] * dn, n1 = dinv[s1] * dn;
        unsigned h0 = *(const unsigned*)(h + (long)s0 * 64 + l * 2);
        unsigned h1 = *(const unsigned*)(h + (long)s1 * 64 + l * 2);
        a0 += bf2f((unsigned short)(h0 & 0xffffu)) * n0;
        a1 += bf2f((unsigned short)(h0 >> 16)) * n0;
        a0 += bf2f((unsigned short)(h1 & 0xffffu)) * n1;
        a1 += bf2f((unsigned short)(h1 >> 16)) * n1;
    }
    if (i < end) {
        int s0 = esrc[i];
        float n0 = dinv[s0] * dn;
        unsigned h0 = *(const unsigned*)(h + (long)s0 * 64 + l * 2);
        a0 += bf2f((unsigned short)(h0 & 0xffffu)) * n0;
        a1 += bf2f((unsigned short)(h0 >> 16)) * n0;
    }

    a0 += bias[l * 2];
    a1 += bias[l * 2 + 1];
    // fused PReLU
    float al0 = alpha[l * 2], al1 = alpha[l * 2 + 1];
    a0 = a0 >= 0.f ? a0 : al0 * a0;
    a1 = a1 >= 0.f ? a1 : al1 * a1;
    float2* op = (float2*)(out + (long)node * 64 + l * 2);
    *op = make_float2(a0, a1);
}

extern "C" void kernel_launch(void* const* d_in, const int* in_sizes, int n_in,
                              void* d_out, int out_size, void* d_ws, size_t ws_size,
                              hipStream_t stream) {
    const float* x     = (const float*)d_in[0];
    const int*   ei    = (const int*)d_in[1];
    const float* W1    = (const float*)d_in[2];
    const float* b1    = (const float*)d_in[3];
    const float* W2    = (const float*)d_in[4];
    const float* b2    = (const float*)d_in[5];
    const float* alpha = (const float*)d_in[6];
    float* out = (float*)d_out;

    char* ws = (char*)d_ws;
    float* dinv         = (float*)(ws);                 // 400,384 B
    int*   row_ptr      = (int*)(ws + 400384);          // 400,384 B (NN+1 ints)
    int*   cnt          = (int*)(ws + 800768);          // 400,384 B (reused as cursor)
    int*   bsum         = (int*)(ws + 1201152);         // 512 B
    int*   esrc         = (int*)(ws + 1201664);         // 6,400,000 B
    unsigned short* hbf = (unsigned short*)(ws + 7601664);  // 12,800,000 B
    float* agg          = (float*)(ws + 20401664);      // 25,600,000 B

    const int NB = (NN + 1023) / 1024;  // 98

    hipMemsetAsync(cnt, 0, NN * sizeof(int), stream);
    k_hist<<<(NE + 255) / 256, 256, 0, stream>>>(ei, cnt);
    k_dinv<<<(NN + 255) / 256, 256, 0, stream>>>(cnt, dinv);
    k_scan1<<<NB, 1024, 0, stream>>>(cnt, row_ptr, bsum);
    k_scan2<<<1, 128, 0, stream>>>(bsum, NB);
    k_scan3<<<NB, 1024, 0, stream>>>(row_ptr, bsum, cnt);  // cnt becomes cursor
    k_scatter<<<(NE + 255) / 256, 256, 0, stream>>>(ei, cnt, esrc);

    // layer 1
    k_mm<128><<<(NN + 63) / 64, 256, 0, stream>>>(x, W1, hbf);
    k_agg<<<(NN + 7) / 8, 256, 0, stream>>>(row_ptr, esrc, hbf, dinv, b1, alpha, agg);
    // layer 2 (agg already PReLU'd)
    k_mm<64><<<(NN + 63) / 64, 256, 0, stream>>>(agg, W2, hbf);
    k_agg<<<(NN + 7) / 8, 256, 0, stream>>>(row_ptr, esrc, hbf, dinv, b2, alpha, out);
}

// Round 3
// 297.784 us; speedup vs baseline: 5.1483x; 1.4882x over previous
//
#include <hip/hip_runtime.h>
#include <hip/hip_bf16.h>

#define NN 100000
#define NE 1600000
#define NBUCK 98  // ceil(NN / 1024)

typedef __attribute__((ext_vector_type(8))) short short8;
typedef __attribute__((ext_vector_type(4))) float f32x4;

static __device__ __forceinline__ unsigned short f2bf(float f) {
    unsigned u = __float_as_uint(f);
    unsigned r = (u + 0x7fffu + ((u >> 16) & 1u)) >> 16;
    return (unsigned short)r;
}
static __device__ __forceinline__ float bf2f(unsigned short s) {
    return __uint_as_float(((unsigned)s) << 16);
}

// ---------- bucketed CSR build ----------
// bucket = dst >> 10 (1024 nodes per bucket)
__global__ __launch_bounds__(256) void k_bcount(const int* __restrict__ ei,
                                                int* __restrict__ bcnt) {
    __shared__ int h[NBUCK];
    int tid = threadIdx.x;
    for (int i = tid; i < NBUCK; i += 256) h[i] = 0;
    __syncthreads();
    for (int e = blockIdx.x * 256 + tid; e < NE; e += gridDim.x * 256)
        atomicAdd(&h[ei[NE + e] >> 10], 1);
    __syncthreads();
    for (int i = tid; i < NBUCK; i += 256) atomicAdd(&bcnt[i], h[i]);
}

__global__ __launch_bounds__(128) void k_bbase(const int* __restrict__ bcnt,
                                               int* __restrict__ bbase,
                                               int* __restrict__ bcur) {
    __shared__ int s[128];
    int tid = threadIdx.x;
    int v = (tid < NBUCK) ? bcnt[tid] : 0;
    s[tid] = v;
    __syncthreads();
    #pragma unroll
    for (int off = 1; off < 128; off <<= 1) {
        int t = (tid >= off) ? s[tid - off] : 0;
        __syncthreads();
        s[tid] += t;
        __syncthreads();
    }
    if (tid < NBUCK) {
        int ex = s[tid] - v;
        bbase[tid] = ex;
        bcur[tid] = ex;
    }
}

#define CHUNK 8192
__global__ __launch_bounds__(256) void k_partition(const int* __restrict__ ei,
                                                   int* __restrict__ bcur,
                                                   unsigned* __restrict__ ebuf) {
    __shared__ int lh[NBUCK];
    __shared__ int lbase[NBUCK];
    int tid = threadIdx.x;
    int e0 = blockIdx.x * CHUNK;
    for (int i = tid; i < NBUCK; i += 256) lh[i] = 0;
    __syncthreads();
    #pragma unroll 4
    for (int k = 0; k < CHUNK; k += 256) {
        int e = e0 + k + tid;
        if (e < NE) atomicAdd(&lh[ei[NE + e] >> 10], 1);
    }
    __syncthreads();
    if (tid < NBUCK) {
        int c = lh[tid];
        lbase[tid] = c ? atomicAdd(&bcur[tid], c) : 0;
        lh[tid] = 0;  // becomes local rank counter
    }
    __syncthreads();
    #pragma unroll 4
    for (int k = 0; k < CHUNK; k += 256) {
        int e = e0 + k + tid;
        if (e < NE) {
            int d = ei[NE + e];
            int s = ei[e];
            int b = d >> 10;
            int r = atomicAdd(&lh[b], 1);
            ebuf[lbase[b] + r] = ((unsigned)s << 10) | (unsigned)(d & 1023);
        }
    }
}

// one block per bucket: per-node counts -> row_ptr/dinv -> scatter src to esrc
__global__ __launch_bounds__(1024) void k_build(const int* __restrict__ bbase,
                                                const int* __restrict__ bcnt,
                                                const unsigned* __restrict__ ebuf,
                                                int* __restrict__ row_ptr,
                                                float* __restrict__ dinv,
                                                int* __restrict__ esrc) {
    __shared__ int cnt[1024];
    __shared__ int s[1024];
    int tid = threadIdx.x;
    int base = bbase[blockIdx.x];
    int nedge = bcnt[blockIdx.x];
    cnt[tid] = 0;
    __syncthreads();
    for (int j = tid; j < nedge; j += 1024)
        atomicAdd(&cnt[ebuf[base + j] & 1023u], 1);
    __syncthreads();
    int v = cnt[tid];
    s[tid] = v;
    __syncthreads();
    #pragma unroll
    for (int off = 1; off < 1024; off <<= 1) {
        int t = (tid >= off) ? s[tid - off] : 0;
        __syncthreads();
        s[tid] += t;
        __syncthreads();
    }
    int ex = s[tid] - v;
    int node = blockIdx.x * 1024 + tid;
    if (node < NN) {
        row_ptr[node] = base + ex;
        dinv[node] = rsqrtf((float)(v + 1));  // +1 self-loop
    }
    if (blockIdx.x == 0 && tid == 0) row_ptr[NN] = NE;
    cnt[tid] = base + ex;  // becomes cursor
    __syncthreads();
    for (int j = tid; j < nedge; j += 1024) {
        unsigned p = ebuf[base + j];
        int pos = atomicAdd(&cnt[p & 1023u], 1);
        esrc[pos] = (int)(p >> 10);
    }
}

// ---------- h = in @ W  [N x K] @ [K x 64] -> bf16 ----------
template <int K>
__global__ __launch_bounds__(256) void k_mm(const float* __restrict__ in,
                                            const float* __restrict__ W,
                                            unsigned short* __restrict__ hout) {
    constexpr int KP = K + 8;  // 2-way bank alias only (free)
    __shared__ unsigned short Wt[64 * KP];
    int tid = threadIdx.x;
    for (int idx = tid; idx < K * 64; idx += 256) {
        int k = idx >> 6, n = idx & 63;
        Wt[n * KP + k] = f2bf(W[idx]);
    }
    __syncthreads();

    int wave = tid >> 6, lane = tid & 63;
    int m = lane & 15, q = lane >> 4;
    int n0 = blockIdx.x * 64 + wave * 16;

    f32x4 acc[4] = {{0.f,0.f,0.f,0.f},{0.f,0.f,0.f,0.f},{0.f,0.f,0.f,0.f},{0.f,0.f,0.f,0.f}};
    int row = n0 + m;
    int rowc = row < NN ? row : NN - 1;
    const float* xr = in + (long)rowc * K;

    #pragma unroll
    for (int kk = 0; kk < K / 32; ++kk) {
        const float4* p = (const float4*)(xr + kk * 32 + q * 8);
        float4 v0 = p[0], v1 = p[1];
        float xv[8] = {v0.x, v0.y, v0.z, v0.w, v1.x, v1.y, v1.z, v1.w};
        short8 afrag;
        #pragma unroll
        for (int i2 = 0; i2 < 8; ++i2) afrag[i2] = (short)f2bf(xv[i2]);
        #pragma unroll
        for (int nt = 0; nt < 4; ++nt) {
            const short8* bp = (const short8*)&Wt[(nt * 16 + m) * KP + kk * 32 + q * 8];
            acc[nt] = __builtin_amdgcn_mfma_f32_16x16x32_bf16(afrag, *bp, acc[nt], 0, 0, 0);
        }
    }

    // D layout: col=lane&15, row=(lane>>4)*4+reg  [m89-verified]
    #pragma unroll
    for (int reg = 0; reg < 4; ++reg) {
        int node = n0 + q * 4 + reg;
        if (node < NN) {
            #pragma unroll
            for (int nt = 0; nt < 4; ++nt)
                hout[(long)node * 64 + nt * 16 + m] = f2bf(acc[nt][reg]);
        }
    }
}

// ---------- per-node aggregation: half-wave per node, fp32 registers ----------
__global__ __launch_bounds__(256) void k_agg(const int* __restrict__ row_ptr,
                                             const int* __restrict__ esrc,
                                             const unsigned short* __restrict__ h,
                                             const float* __restrict__ dinv,
                                             const float* __restrict__ bias,
                                             const float* __restrict__ alpha,
                                             float* __restrict__ out) {
    int node = blockIdx.x * 8 + (threadIdx.x >> 5);
    int l = threadIdx.x & 31;
    if (node >= NN) return;
    int start = row_ptr[node], end = row_ptr[node + 1];
    float dn = dinv[node];

    // self-loop: norm = dinv[node]^2
    unsigned hv = *(const unsigned*)(h + (long)node * 64 + l * 2);
    float d2 = dn * dn;
    float a0 = bf2f((unsigned short)(hv & 0xffffu)) * d2;
    float a1 = bf2f((unsigned short)(hv >> 16)) * d2;

    int i = start;
    for (; i + 1 < end; i += 2) {
        int s0 = esrc[i], s1 = esrc[i + 1];
        float n0 = dinv[s0] * dn, n1 = dinv[s1] * dn;
        unsigned h0 = *(const unsigned*)(h + (long)s0 * 64 + l * 2);
        unsigned h1 = *(const unsigned*)(h + (long)s1 * 64 + l * 2);
        a0 += bf2f((unsigned short)(h0 & 0xffffu)) * n0;
        a1 += bf2f((unsigned short)(h0 >> 16)) * n0;
        a0 += bf2f((unsigned short)(h1 & 0xffffu)) * n1;
        a1 += bf2f((unsigned short)(h1 >> 16)) * n1;
    }
    if (i < end) {
        int s0 = esrc[i];
        float n0 = dinv[s0] * dn;
        unsigned h0 = *(const unsigned*)(h + (long)s0 * 64 + l * 2);
        a0 += bf2f((unsigned short)(h0 & 0xffffu)) * n0;
        a1 += bf2f((unsigned short)(h0 >> 16)) * n0;
    }

    a0 += bias[l * 2];
    a1 += bias[l * 2 + 1];
    float al0 = alpha[l * 2], al1 = alpha[l * 2 + 1];
    a0 = a0 >= 0.f ? a0 : al0 * a0;
    a1 = a1 >= 0.f ? a1 : al1 * a1;
    float2* op = (float2*)(out + (long)node * 64 + l * 2);
    *op = make_float2(a0, a1);
}

extern "C" void kernel_launch(void* const* d_in, const int* in_sizes, int n_in,
                              void* d_out, int out_size, void* d_ws, size_t ws_size,
                              hipStream_t stream) {
    const float* x     = (const float*)d_in[0];
    const int*   ei    = (const int*)d_in[1];
    const float* W1    = (const float*)d_in[2];
    const float* b1    = (const float*)d_in[3];
    const float* W2    = (const float*)d_in[4];
    const float* b2    = (const float*)d_in[5];
    const float* alpha = (const float*)d_in[6];
    float* out = (float*)d_out;

    char* ws = (char*)d_ws;
    float* dinv         = (float*)(ws);                     //       0: 400,384 B
    int*   row_ptr      = (int*)(ws + 400384);              //  400384: 400,128 B (NN+1)
    int*   bcnt         = (int*)(ws + 800512);              //  800512: 512 B
    int*   bbase        = (int*)(ws + 801024);              //  801024: 512 B
    int*   bcur         = (int*)(ws + 801536);              //  801536: 512 B
    int*   esrc         = (int*)(ws + 802048);              //  802048: 6,400,000 B
    unsigned short* hbf = (unsigned short*)(ws + 7202048);  // 7202048: 12,800,000 B
    unsigned* ebuf      = (unsigned*)(ws + 20002048);       // 20002048: 6,400,000 B (dead after k_build)
    float* agg          = (float*)(ws + 20002048);          // aliases ebuf: 25,600,000 B
    // total: 45,602,048 B

    hipMemsetAsync(bcnt, 0, NBUCK * sizeof(int), stream);
    k_bcount<<<256, 256, 0, stream>>>(ei, bcnt);
    k_bbase<<<1, 128, 0, stream>>>(bcnt, bbase, bcur);
    k_partition<<<(NE + CHUNK - 1) / CHUNK, 256, 0, stream>>>(ei, bcur, ebuf);
    k_build<<<NBUCK, 1024, 0, stream>>>(bbase, bcnt, ebuf, row_ptr, dinv, esrc);

    // layer 1
    k_mm<128><<<(NN + 63) / 64, 256, 0, stream>>>(x, W1, hbf);
    k_agg<<<(NN + 7) / 8, 256, 0, stream>>>(row_ptr, esrc, hbf, dinv, b1, alpha, agg);
    // layer 2 (agg already PReLU'd)
    k_mm<64><<<(NN + 63) / 64, 256, 0, stream>>>(agg, W2, hbf);
    k_agg<<<(NN + 7) / 8, 256, 0, stream>>>(row_ptr, esrc, hbf, dinv, b2, alpha, out);
}